// Round 1
// baseline (2294.853 us; speedup 1.0000x reference)
//
#include <hip/hip_runtime.h>

#define EPS 1e-5f

// ---------------------------------------------------------------- utilities
__global__ void zero_kernel(int* __restrict__ counts, float* __restrict__ stats,
                            int n_counts, int n_stats) {
    int i = blockIdx.x * 256 + threadIdx.x;
    if (i < n_counts) counts[i] = 0;
    if (i < n_stats)  stats[i]  = 0.0f;
}

__global__ void hist_kernel(const int* __restrict__ erow, int* __restrict__ counts, int E) {
    int e = blockIdx.x * 256 + threadIdx.x;
    if (e < E) atomicAdd(&counts[erow[e]], 1);
}

// single-block exclusive scan over counts -> row_start[n+1], cursor[n]
__global__ __launch_bounds__(1024) void scan_kernel(const int* __restrict__ counts,
                                                    int* __restrict__ row_start,
                                                    int* __restrict__ cursor, int n) {
    __shared__ int lds[1024];
    int t = threadIdx.x;
    int per = (n + 1023) >> 10;
    int s0 = t * per;
    int s1 = min(s0 + per, n);
    int sum = 0;
    for (int i = s0; i < s1; i++) sum += counts[i];
    lds[t] = sum;
    __syncthreads();
    for (int off = 1; off < 1024; off <<= 1) {
        int v = (t >= off) ? lds[t - off] : 0;
        __syncthreads();
        lds[t] += v;
        __syncthreads();
    }
    int run = lds[t] - sum;  // exclusive prefix
    for (int i = s0; i < s1; i++) {
        row_start[i] = run;
        cursor[i]    = run;
        run += counts[i];
    }
    if (t == 0) row_start[n] = lds[1023];
}

__global__ void scatter_kernel(const int* __restrict__ erow, const int* __restrict__ ecol,
                               const float* __restrict__ eval_, int* __restrict__ cursor,
                               int* __restrict__ scol, float* __restrict__ sval, int E) {
    int e = blockIdx.x * 256 + threadIdx.x;
    if (e < E) {
        int r = erow[e];
        int p = atomicAdd(&cursor[r], 1);
        scol[p] = ecol[e];
        sval[p] = eval_[e];
    }
}

// ---------------------------------------------------------------- GEMM1: [M,512] @ [512,256]
// BM=128, BN=128, BK=8, 256 threads, 8x8 microtile
__global__ __launch_bounds__(256) void gemm1_kernel(const float* __restrict__ A,
                                                    const float* __restrict__ B,
                                                    float* __restrict__ C, int M) {
    __shared__ float As[8][129];
    __shared__ float Bs[8][128];
    int tid = threadIdx.x;
    int tx = tid & 15, ty = tid >> 4;
    int rowBase = blockIdx.y * 128;
    int colBase = blockIdx.x * 128;
    float acc[8][8];
#pragma unroll
    for (int i = 0; i < 8; i++)
#pragma unroll
        for (int j = 0; j < 8; j++) acc[i][j] = 0.0f;

    int r   = tid >> 1;
    int kq  = (tid & 1) * 4;
    int bkk = tid >> 7;       // 0..1
    int bcol = tid & 127;

    for (int k0 = 0; k0 < 512; k0 += 8) {
        float4 a4 = make_float4(0.f, 0.f, 0.f, 0.f);
        int arow = rowBase + r;
        if (arow < M) a4 = *(const float4*)(A + (size_t)arow * 512 + k0 + kq);
        As[kq + 0][r] = a4.x; As[kq + 1][r] = a4.y;
        As[kq + 2][r] = a4.z; As[kq + 3][r] = a4.w;
#pragma unroll
        for (int j = 0; j < 4; j++)
            Bs[bkk + j * 2][bcol] = B[(size_t)(k0 + bkk + j * 2) * 256 + colBase + bcol];
        __syncthreads();
#pragma unroll
        for (int k = 0; k < 8; k++) {
            float ra[8], rb[8];
#pragma unroll
            for (int i = 0; i < 8; i++) ra[i] = As[k][ty * 8 + i];
#pragma unroll
            for (int j = 0; j < 8; j++) rb[j] = Bs[k][tx * 8 + j];
#pragma unroll
            for (int i = 0; i < 8; i++)
#pragma unroll
                for (int j = 0; j < 8; j++) acc[i][j] += ra[i] * rb[j];
        }
        __syncthreads();
    }
#pragma unroll
    for (int i = 0; i < 8; i++) {
        int crow = rowBase + ty * 8 + i;
        if (crow < M) {
            float4 v0 = make_float4(acc[i][0], acc[i][1], acc[i][2], acc[i][3]);
            float4 v1 = make_float4(acc[i][4], acc[i][5], acc[i][6], acc[i][7]);
            *(float4*)(C + (size_t)crow * 256 + colBase + tx * 8)     = v0;
            *(float4*)(C + (size_t)crow * 256 + colBase + tx * 8 + 4) = v1;
        }
    }
}

// ---------------------------------------------------------------- SpMM1 (F=256): block per row
__global__ __launch_bounds__(256) void agg1_kernel(const float* __restrict__ H0,
                                                   const int* __restrict__ rs,
                                                   const int* __restrict__ scol,
                                                   const float* __restrict__ sval,
                                                   float* __restrict__ H1) {
    int i = blockIdx.x;
    int tid = threadIdx.x;
    int start = rs[i], end = rs[i + 1];
    float acc = 0.0f;
    for (int j = start; j < end; j++) {
        int c   = scol[j];
        float v = sval[j];
        acc += v * H0[(size_t)c * 256 + tid];
    }
    H1[(size_t)i * 256 + tid] = fmaxf(acc, 0.0f);  // relu
}

// ---------------------------------------------------------------- column stats F=256
__global__ __launch_bounds__(256) void colstats1_kernel(const float* __restrict__ H1,
                                                        float* __restrict__ sums,
                                                        float* __restrict__ sumsq,
                                                        int n, int rpb) {
    int tid = threadIdx.x;
    int r0 = blockIdx.x * rpb;
    int r1 = min(r0 + rpb, n);
    float s = 0.f, q = 0.f;
    for (int rr = r0; rr < r1; rr++) {
        float v = H1[(size_t)rr * 256 + tid];
        s += v; q += v * v;
    }
    atomicAdd(&sums[tid], s);
    atomicAdd(&sumsq[tid], q);
}

__global__ void bnparams_kernel(const float* __restrict__ sums, const float* __restrict__ sumsq,
                                const float* __restrict__ gamma, const float* __restrict__ beta,
                                float* __restrict__ scale, float* __restrict__ shift,
                                int C, float invN) {
    int c = threadIdx.x;
    if (c < C) {
        float mean = sums[c] * invN;
        float var  = sumsq[c] * invN - mean * mean;
        float rstd = rsqrtf(var + EPS);
        float sc   = gamma[c] * rstd;
        scale[c] = sc;
        shift[c] = beta[c] - mean * sc;
    }
}

// ---------------------------------------------------------------- GEMM2: relu(bn1(H1)) @ W2
// BM=128, BN=64(full), BK=8, 256 threads, 8x4 microtile
__global__ __launch_bounds__(256) void gemm2_kernel(const float* __restrict__ H1,
                                                    const float* __restrict__ W2,
                                                    const float* __restrict__ scale1,
                                                    const float* __restrict__ shift1,
                                                    float* __restrict__ H2, int M) {
    __shared__ float As[8][129];
    __shared__ float Bs[8][64];
    int tid = threadIdx.x;
    int tx = tid & 15, ty = tid >> 4;
    int rowBase = blockIdx.x * 128;
    float acc[8][4];
#pragma unroll
    for (int i = 0; i < 8; i++)
#pragma unroll
        for (int j = 0; j < 4; j++) acc[i][j] = 0.0f;

    int r   = tid >> 1;
    int kq  = (tid & 1) * 4;
    int bkk = tid >> 6;       // 0..3
    int bcol = tid & 63;

    for (int k0 = 0; k0 < 256; k0 += 8) {
        float4 a4 = make_float4(0.f, 0.f, 0.f, 0.f);
        int arow = rowBase + r;
        if (arow < M) a4 = *(const float4*)(H1 + (size_t)arow * 256 + k0 + kq);
        float av[4] = {a4.x, a4.y, a4.z, a4.w};
#pragma unroll
        for (int jj = 0; jj < 4; jj++) {
            int kk = k0 + kq + jj;
            float t = av[jj] * scale1[kk] + shift1[kk];
            As[kq + jj][r] = fmaxf(t, 0.0f);
        }
        Bs[bkk][bcol]     = W2[(size_t)(k0 + bkk) * 64 + bcol];
        Bs[bkk + 4][bcol] = W2[(size_t)(k0 + bkk + 4) * 64 + bcol];
        __syncthreads();
#pragma unroll
        for (int k = 0; k < 8; k++) {
            float ra[8], rb[4];
#pragma unroll
            for (int i = 0; i < 8; i++) ra[i] = As[k][ty * 8 + i];
#pragma unroll
            for (int j = 0; j < 4; j++) rb[j] = Bs[k][tx * 4 + j];
#pragma unroll
            for (int i = 0; i < 8; i++)
#pragma unroll
                for (int j = 0; j < 4; j++) acc[i][j] += ra[i] * rb[j];
        }
        __syncthreads();
    }
#pragma unroll
    for (int i = 0; i < 8; i++) {
        int crow = rowBase + ty * 8 + i;
        if (crow < M) {
            float4 v0 = make_float4(acc[i][0], acc[i][1], acc[i][2], acc[i][3]);
            *(float4*)(H2 + (size_t)crow * 64 + tx * 4) = v0;
        }
    }
}

// ---------------------------------------------------------------- SpMM2 (F=64): wave per row
__global__ __launch_bounds__(256) void agg2_kernel(const float* __restrict__ H2,
                                                   const int* __restrict__ rs,
                                                   const int* __restrict__ scol,
                                                   const float* __restrict__ sval,
                                                   float* __restrict__ H3, int n) {
    int w = threadIdx.x >> 6, lane = threadIdx.x & 63;
    int i = blockIdx.x * 4 + w;
    if (i >= n) return;
    int start = rs[i], end = rs[i + 1];
    float acc = 0.0f;
    for (int j = start; j < end; j++) {
        acc += sval[j] * H2[(size_t)scol[j] * 64 + lane];
    }
    H3[(size_t)i * 64 + lane] = fmaxf(acc, 0.0f);  // relu
}

// ---------------------------------------------------------------- column stats F=64
__global__ __launch_bounds__(256) void colstats2_kernel(const float* __restrict__ H3,
                                                        float* __restrict__ sums,
                                                        float* __restrict__ sumsq,
                                                        int n, int rpb) {
    int c = threadIdx.x & 63, rsub = threadIdx.x >> 6;
    int base = blockIdx.x * rpb;
    int r1 = min(base + rpb, n);
    float s = 0.f, q = 0.f;
    for (int rr = base + rsub; rr < r1; rr += 4) {
        float v = H3[(size_t)rr * 64 + c];
        s += v; q += v * v;
    }
    atomicAdd(&sums[c], s);
    atomicAdd(&sumsq[c], q);
}

__global__ void bnapply_kernel(float* __restrict__ out, const float* __restrict__ scale,
                               const float* __restrict__ shift, int total) {
    int idx = blockIdx.x * 256 + threadIdx.x;
    if (idx < total) {
        int c = idx & 63;
        out[idx] = out[idx] * scale[c] + shift[c];
    }
}

// ---------------------------------------------------------------- launch
extern "C" void kernel_launch(void* const* d_in, const int* in_sizes, int n_in,
                              void* d_out, int out_size, void* d_ws, size_t ws_size,
                              hipStream_t stream) {
    const float* x    = (const float*)d_in[0];
    const int*   erow = (const int*)d_in[1];
    const int*   ecol = (const int*)d_in[2];
    const float* ev   = (const float*)d_in[3];
    const float* W1   = (const float*)d_in[4];
    const float* g1   = (const float*)d_in[5];
    const float* b1   = (const float*)d_in[6];
    const float* W2   = (const float*)d_in[7];
    const float* g2   = (const float*)d_in[8];
    const float* b2   = (const float*)d_in[9];
    float* out = (float*)d_out;

    int n = in_sizes[0] / 512;   // 100000
    int E = in_sizes[1];         // 3200000

    char* ws = (char*)d_ws;
    size_t off = 0;
    auto alloc = [&](size_t bytes) { size_t o = off; off += (bytes + 255) & ~(size_t)255; return o; };

    int*   counts    = (int*)(ws + alloc((size_t)n * 4));
    int*   row_start = (int*)(ws + alloc((size_t)(n + 1) * 4));
    int*   cursor    = (int*)(ws + alloc((size_t)n * 4));
    int*   scol      = (int*)(ws + alloc((size_t)E * 4));
    float* sval      = (float*)(ws + alloc((size_t)E * 4));
    float* h0        = (float*)(ws + alloc((size_t)n * 256 * 4));
    float* h1        = (float*)(ws + alloc((size_t)n * 256 * 4));
    float* h2        = (float*)(ws + alloc((size_t)n * 64 * 4));
    float* stats     = (float*)(ws + alloc(2048 * 4));
    // stats layout: sums1[256] sumsq1[256] sums2[64] sumsq2[64] scale1[256] shift1[256] scale2[64] shift2[64]
    float* sums1  = stats;
    float* sumsq1 = stats + 256;
    float* sums2  = stats + 512;
    float* sumsq2 = stats + 576;
    float* scale1 = stats + 640;
    float* shift1 = stats + 896;
    float* scale2 = stats + 1152;
    float* shift2 = stats + 1216;

    float invN = 1.0f / (float)n;

    // 1. zero counts + stat accumulators
    zero_kernel<<<dim3((n + 255) / 256), dim3(256), 0, stream>>>(counts, stats, n, 640);
    // 2. histogram of rows
    hist_kernel<<<dim3((E + 255) / 256), dim3(256), 0, stream>>>(erow, counts, E);
    // 3. prefix sum -> CSR row_start + cursor
    scan_kernel<<<dim3(1), dim3(1024), 0, stream>>>(counts, row_start, cursor, n);
    // 4. scatter edges into CSR order
    scatter_kernel<<<dim3((E + 255) / 256), dim3(256), 0, stream>>>(erow, ecol, ev, cursor, scol, sval, E);
    // 5. h0 = x @ W1
    gemm1_kernel<<<dim3(2, (n + 127) / 128), dim3(256), 0, stream>>>(x, W1, h0, n);
    // 6. h1 = relu(spmm(h0))
    agg1_kernel<<<dim3(n), dim3(256), 0, stream>>>(h0, row_start, scol, sval, h1);
    // 7. BN1 stats
    colstats1_kernel<<<dim3(400), dim3(256), 0, stream>>>(h1, sums1, sumsq1, n, (n + 399) / 400);
    // 8. BN1 params
    bnparams_kernel<<<dim3(1), dim3(256), 0, stream>>>(sums1, sumsq1, g1, b1, scale1, shift1, 256, invN);
    // 9. h2 = relu(bn1(h1)) @ W2
    gemm2_kernel<<<dim3((n + 127) / 128), dim3(256), 0, stream>>>(h1, W2, scale1, shift1, h2, n);
    // 10. out_pre = relu(spmm(h2))  (written into d_out)
    agg2_kernel<<<dim3((n + 3) / 4), dim3(256), 0, stream>>>(h2, row_start, scol, sval, out, n);
    // 11. BN2 stats
    colstats2_kernel<<<dim3(200), dim3(256), 0, stream>>>(out, sums2, sumsq2, n, (n + 199) / 200);
    // 12. BN2 params
    bnparams_kernel<<<dim3(1), dim3(64), 0, stream>>>(sums2, sumsq2, g2, b2, scale2, shift2, 64, invN);
    // 13. in-place BN apply on d_out
    bnapply_kernel<<<dim3((n * 64 + 255) / 256), dim3(256), 0, stream>>>(out, scale2, shift2, n * 64);

    (void)n_in; (void)out_size; (void)ws_size;
}

// Round 2
// 1693.211 us; speedup vs baseline: 1.3553x; 1.3553x over previous
//
#include <hip/hip_runtime.h>

#define EPS 1e-5f

typedef __attribute__((ext_vector_type(8))) short short8;
typedef __attribute__((ext_vector_type(4))) float floatx4;

__device__ __forceinline__ unsigned short f2bf(float f) {
    unsigned u = __float_as_uint(f);
    unsigned r = (u + 0x7FFFu + ((u >> 16) & 1u)) >> 16;
    return (unsigned short)r;
}

// ---------------------------------------------------------------- utilities
__global__ void zero_kernel(int* __restrict__ counts, float* __restrict__ stats,
                            int n_counts, int n_stats) {
    int i = blockIdx.x * 256 + threadIdx.x;
    if (i < n_counts) counts[i] = 0;
    if (i < n_stats)  stats[i]  = 0.0f;
}

__global__ void hist_kernel(const int* __restrict__ erow, int* __restrict__ counts, int E) {
    int e = blockIdx.x * 256 + threadIdx.x;
    if (e < E) atomicAdd(&counts[erow[e]], 1);
}

// single-block exclusive scan over counts -> row_start[n+1], cursor[n]
__global__ __launch_bounds__(1024) void scan_kernel(const int* __restrict__ counts,
                                                    int* __restrict__ row_start,
                                                    int* __restrict__ cursor, int n) {
    __shared__ int lds[1024];
    int t = threadIdx.x;
    int per = (n + 1023) >> 10;
    int s0 = t * per;
    int s1 = min(s0 + per, n);
    int sum = 0;
    for (int i = s0; i < s1; i++) sum += counts[i];
    lds[t] = sum;
    __syncthreads();
    for (int off = 1; off < 1024; off <<= 1) {
        int v = (t >= off) ? lds[t - off] : 0;
        __syncthreads();
        lds[t] += v;
        __syncthreads();
    }
    int run = lds[t] - sum;  // exclusive prefix
    for (int i = s0; i < s1; i++) {
        row_start[i] = run;
        cursor[i]    = run;
        run += counts[i];
    }
    if (t == 0) row_start[n] = lds[1023];
}

__global__ void scatter_kernel(const int* __restrict__ erow, const int* __restrict__ ecol,
                               const float* __restrict__ eval_, int* __restrict__ cursor,
                               int* __restrict__ scol, float* __restrict__ sval, int E) {
    int e = blockIdx.x * 256 + threadIdx.x;
    if (e < E) {
        int r = erow[e];
        int p = atomicAdd(&cursor[r], 1);
        scol[p] = ecol[e];
        sval[p] = eval_[e];
    }
}

// ---------------------------------------------------------------- W1 -> bf16 transposed [256][512]
__global__ void prep_w1_kernel(const float* __restrict__ W1, unsigned short* __restrict__ Bt) {
    int idx = blockIdx.x * 256 + threadIdx.x;   // 131072 total
    int n = idx >> 9, k = idx & 511;
    Bt[idx] = f2bf(W1[(size_t)k * 256 + n]);
}

// ---------------------------------------------------------------- GEMM1 (MFMA bf16):
// C[M,256] = A[M,512] @ W1, A converted fp32->bf16 inline during LDS staging.
// Block 256 thr = 4 waves in 2x2; block tile 128x128; wave tile 64x64 = 4x4 MFMA 16x16x32.
__global__ __launch_bounds__(256) void gemm1_mfma_kernel(const float* __restrict__ A,
                                                         const unsigned short* __restrict__ Bt,
                                                         float* __restrict__ C, int M) {
    __shared__ unsigned short As[128][32];
    __shared__ unsigned short Bs[128][32];
    int tid  = threadIdx.x;
    int lane = tid & 63, w = tid >> 6;
    int wm = w & 1, wn = w >> 1;
    int rowBase = blockIdx.y * 128;
    int colBase = blockIdx.x * 128;

    floatx4 acc[4][4];
#pragma unroll
    for (int i = 0; i < 4; i++)
#pragma unroll
        for (int j = 0; j < 4; j++)
#pragma unroll
            for (int r = 0; r < 4; r++) acc[i][j][r] = 0.0f;

    int r    = tid >> 1;        // 0..127 staging row
    int half = tid & 1;         // which 16-element k-chunk
    bool aval = (rowBase + r) < M;
    const float* aptr = A + (size_t)(rowBase + r) * 512 + half * 16;
    const unsigned short* bptr = Bt + (size_t)(colBase + r) * 512 + half * 16;

    int cl = lane & 15, quad = lane >> 4;
    int q8 = quad * 8;

    for (int k0 = 0; k0 < 512; k0 += 32) {
        // ---- stage A (fp32 -> bf16) : 16 floats per thread
        float4 f0, f1, f2, f3;
        if (aval) {
            f0 = *(const float4*)(aptr + k0);
            f1 = *(const float4*)(aptr + k0 + 4);
            f2 = *(const float4*)(aptr + k0 + 8);
            f3 = *(const float4*)(aptr + k0 + 12);
        } else {
            f0 = f1 = f2 = f3 = make_float4(0.f, 0.f, 0.f, 0.f);
        }
        union { unsigned short s[16]; uint4 q[2]; } pk;
        pk.s[0] = f2bf(f0.x);  pk.s[1] = f2bf(f0.y);  pk.s[2]  = f2bf(f0.z);  pk.s[3]  = f2bf(f0.w);
        pk.s[4] = f2bf(f1.x);  pk.s[5] = f2bf(f1.y);  pk.s[6]  = f2bf(f1.z);  pk.s[7]  = f2bf(f1.w);
        pk.s[8] = f2bf(f2.x);  pk.s[9] = f2bf(f2.y);  pk.s[10] = f2bf(f2.z);  pk.s[11] = f2bf(f2.w);
        pk.s[12] = f2bf(f3.x); pk.s[13] = f2bf(f3.y); pk.s[14] = f2bf(f3.z);  pk.s[15] = f2bf(f3.w);
        *(uint4*)&As[r][half * 16]     = pk.q[0];
        *(uint4*)&As[r][half * 16 + 8] = pk.q[1];
        // ---- stage B (already bf16, pre-transposed [n][k])
        uint4 b0 = *(const uint4*)(bptr + k0);
        uint4 b1 = *(const uint4*)(bptr + k0 + 8);
        *(uint4*)&Bs[r][half * 16]     = b0;
        *(uint4*)&Bs[r][half * 16 + 8] = b1;
        __syncthreads();

        short8 af[4], bf[4];
#pragma unroll
        for (int mt = 0; mt < 4; mt++) af[mt] = *(short8*)&As[wm * 64 + mt * 16 + cl][q8];
#pragma unroll
        for (int nt = 0; nt < 4; nt++) bf[nt] = *(short8*)&Bs[wn * 64 + nt * 16 + cl][q8];
#pragma unroll
        for (int mt = 0; mt < 4; mt++)
#pragma unroll
            for (int nt = 0; nt < 4; nt++)
                acc[mt][nt] = __builtin_amdgcn_mfma_f32_16x16x32_bf16(af[mt], bf[nt], acc[mt][nt], 0, 0, 0);
        __syncthreads();
    }

    // epilogue: C/D layout col=lane&15, row=quad*4+reg
#pragma unroll
    for (int mt = 0; mt < 4; mt++) {
#pragma unroll
        for (int reg = 0; reg < 4; reg++) {
            int gr = rowBase + wm * 64 + mt * 16 + quad * 4 + reg;
            if (gr < M) {
#pragma unroll
                for (int nt = 0; nt < 4; nt++) {
                    C[(size_t)gr * 256 + colBase + wn * 64 + nt * 16 + cl] = acc[mt][nt][reg];
                }
            }
        }
    }
}

// ---------------------------------------------------------------- SpMM1 (F=256): wave per row, float4/lane
__global__ __launch_bounds__(256) void agg1_kernel(const float* __restrict__ H0,
                                                   const int* __restrict__ rs,
                                                   const int* __restrict__ scol,
                                                   const float* __restrict__ sval,
                                                   float* __restrict__ H1, int n) {
    int w = threadIdx.x >> 6, lane = threadIdx.x & 63;
    int i = blockIdx.x * 4 + w;
    if (i >= n) return;
    int start = rs[i], end = rs[i + 1];
    int fo = lane << 2;
    float4 acc = make_float4(0.f, 0.f, 0.f, 0.f);
    int j = start;
    for (; j + 4 <= end; j += 4) {
        int c0 = scol[j], c1 = scol[j + 1], c2 = scol[j + 2], c3 = scol[j + 3];
        float v0 = sval[j], v1 = sval[j + 1], v2 = sval[j + 2], v3 = sval[j + 3];
        float4 r0 = *(const float4*)(H0 + (size_t)c0 * 256 + fo);
        float4 r1 = *(const float4*)(H0 + (size_t)c1 * 256 + fo);
        float4 r2 = *(const float4*)(H0 + (size_t)c2 * 256 + fo);
        float4 r3 = *(const float4*)(H0 + (size_t)c3 * 256 + fo);
        acc.x += v0 * r0.x; acc.y += v0 * r0.y; acc.z += v0 * r0.z; acc.w += v0 * r0.w;
        acc.x += v1 * r1.x; acc.y += v1 * r1.y; acc.z += v1 * r1.z; acc.w += v1 * r1.w;
        acc.x += v2 * r2.x; acc.y += v2 * r2.y; acc.z += v2 * r2.z; acc.w += v2 * r2.w;
        acc.x += v3 * r3.x; acc.y += v3 * r3.y; acc.z += v3 * r3.z; acc.w += v3 * r3.w;
    }
    for (; j < end; j++) {
        int c = scol[j];
        float v = sval[j];
        float4 r0 = *(const float4*)(H0 + (size_t)c * 256 + fo);
        acc.x += v * r0.x; acc.y += v * r0.y; acc.z += v * r0.z; acc.w += v * r0.w;
    }
    float4 o;
    o.x = fmaxf(acc.x, 0.f); o.y = fmaxf(acc.y, 0.f);
    o.z = fmaxf(acc.z, 0.f); o.w = fmaxf(acc.w, 0.f);
    *(float4*)(H1 + (size_t)i * 256 + fo) = o;
}

// ---------------------------------------------------------------- column stats F=256
__global__ __launch_bounds__(256) void colstats1_kernel(const float* __restrict__ H1,
                                                        float* __restrict__ sums,
                                                        float* __restrict__ sumsq,
                                                        int n, int rpb) {
    int tid = threadIdx.x;
    int r0 = blockIdx.x * rpb;
    int r1 = min(r0 + rpb, n);
    float s = 0.f, q = 0.f;
    for (int rr = r0; rr < r1; rr++) {
        float v = H1[(size_t)rr * 256 + tid];
        s += v; q += v * v;
    }
    atomicAdd(&sums[tid], s);
    atomicAdd(&sumsq[tid], q);
}

__global__ void bnparams_kernel(const float* __restrict__ sums, const float* __restrict__ sumsq,
                                const float* __restrict__ gamma, const float* __restrict__ beta,
                                float* __restrict__ scale, float* __restrict__ shift,
                                int C, float invN) {
    int c = threadIdx.x;
    if (c < C) {
        float mean = sums[c] * invN;
        float var  = sumsq[c] * invN - mean * mean;
        float rstd = rsqrtf(var + EPS);
        float sc   = gamma[c] * rstd;
        scale[c] = sc;
        shift[c] = beta[c] - mean * sc;
    }
}

// ---------------------------------------------------------------- GEMM2: relu(bn1(H1)) @ W2
// BM=128, BN=64(full), BK=8, 256 threads, 8x4 microtile (fp32 vector ALU)
__global__ __launch_bounds__(256) void gemm2_kernel(const float* __restrict__ H1,
                                                    const float* __restrict__ W2,
                                                    const float* __restrict__ scale1,
                                                    const float* __restrict__ shift1,
                                                    float* __restrict__ H2, int M) {
    __shared__ float As[8][129];
    __shared__ float Bs[8][64];
    int tid = threadIdx.x;
    int tx = tid & 15, ty = tid >> 4;
    int rowBase = blockIdx.x * 128;
    float acc[8][4];
#pragma unroll
    for (int i = 0; i < 8; i++)
#pragma unroll
        for (int j = 0; j < 4; j++) acc[i][j] = 0.0f;

    int r   = tid >> 1;
    int kq  = (tid & 1) * 4;
    int bkk = tid >> 6;       // 0..3
    int bcol = tid & 63;

    for (int k0 = 0; k0 < 256; k0 += 8) {
        float4 a4 = make_float4(0.f, 0.f, 0.f, 0.f);
        int arow = rowBase + r;
        if (arow < M) a4 = *(const float4*)(H1 + (size_t)arow * 256 + k0 + kq);
        float av[4] = {a4.x, a4.y, a4.z, a4.w};
#pragma unroll
        for (int jj = 0; jj < 4; jj++) {
            int kk = k0 + kq + jj;
            float t = av[jj] * scale1[kk] + shift1[kk];
            As[kq + jj][r] = fmaxf(t, 0.0f);
        }
        Bs[bkk][bcol]     = W2[(size_t)(k0 + bkk) * 64 + bcol];
        Bs[bkk + 4][bcol] = W2[(size_t)(k0 + bkk + 4) * 64 + bcol];
        __syncthreads();
#pragma unroll
        for (int k = 0; k < 8; k++) {
            float ra[8], rb[4];
#pragma unroll
            for (int i = 0; i < 8; i++) ra[i] = As[k][ty * 8 + i];
#pragma unroll
            for (int j = 0; j < 4; j++) rb[j] = Bs[k][tx * 4 + j];
#pragma unroll
            for (int i = 0; i < 8; i++)
#pragma unroll
                for (int j = 0; j < 4; j++) acc[i][j] += ra[i] * rb[j];
        }
        __syncthreads();
    }
#pragma unroll
    for (int i = 0; i < 8; i++) {
        int crow = rowBase + ty * 8 + i;
        if (crow < M) {
            float4 v0 = make_float4(acc[i][0], acc[i][1], acc[i][2], acc[i][3]);
            *(float4*)(H2 + (size_t)crow * 64 + tx * 4) = v0;
        }
    }
}

// ---------------------------------------------------------------- SpMM2 (F=64): wave per row, 4-edge unroll
__global__ __launch_bounds__(256) void agg2_kernel(const float* __restrict__ H2,
                                                   const int* __restrict__ rs,
                                                   const int* __restrict__ scol,
                                                   const float* __restrict__ sval,
                                                   float* __restrict__ H3, int n) {
    int w = threadIdx.x >> 6, lane = threadIdx.x & 63;
    int i = blockIdx.x * 4 + w;
    if (i >= n) return;
    int start = rs[i], end = rs[i + 1];
    float acc = 0.0f;
    int j = start;
    for (; j + 4 <= end; j += 4) {
        int c0 = scol[j], c1 = scol[j + 1], c2 = scol[j + 2], c3 = scol[j + 3];
        float v0 = sval[j], v1 = sval[j + 1], v2 = sval[j + 2], v3 = sval[j + 3];
        float r0 = H2[(size_t)c0 * 64 + lane];
        float r1 = H2[(size_t)c1 * 64 + lane];
        float r2 = H2[(size_t)c2 * 64 + lane];
        float r3 = H2[(size_t)c3 * 64 + lane];
        acc += v0 * r0 + v1 * r1 + v2 * r2 + v3 * r3;
    }
    for (; j < end; j++) {
        acc += sval[j] * H2[(size_t)scol[j] * 64 + lane];
    }
    H3[(size_t)i * 64 + lane] = fmaxf(acc, 0.0f);  // relu
}

// ---------------------------------------------------------------- column stats F=64
__global__ __launch_bounds__(256) void colstats2_kernel(const float* __restrict__ H3,
                                                        float* __restrict__ sums,
                                                        float* __restrict__ sumsq,
                                                        int n, int rpb) {
    int c = threadIdx.x & 63, rsub = threadIdx.x >> 6;
    int base = blockIdx.x * rpb;
    int r1 = min(base + rpb, n);
    float s = 0.f, q = 0.f;
    for (int rr = base + rsub; rr < r1; rr += 4) {
        float v = H3[(size_t)rr * 64 + c];
        s += v; q += v * v;
    }
    atomicAdd(&sums[c], s);
    atomicAdd(&sumsq[c], q);
}

__global__ void bnapply_kernel(float* __restrict__ out, const float* __restrict__ scale,
                               const float* __restrict__ shift, int total) {
    int idx = blockIdx.x * 256 + threadIdx.x;
    if (idx < total) {
        int c = idx & 63;
        out[idx] = out[idx] * scale[c] + shift[c];
    }
}

// ---------------------------------------------------------------- launch
extern "C" void kernel_launch(void* const* d_in, const int* in_sizes, int n_in,
                              void* d_out, int out_size, void* d_ws, size_t ws_size,
                              hipStream_t stream) {
    const float* x    = (const float*)d_in[0];
    const int*   erow = (const int*)d_in[1];
    const int*   ecol = (const int*)d_in[2];
    const float* ev   = (const float*)d_in[3];
    const float* W1   = (const float*)d_in[4];
    const float* g1   = (const float*)d_in[5];
    const float* b1   = (const float*)d_in[6];
    const float* W2   = (const float*)d_in[7];
    const float* g2   = (const float*)d_in[8];
    const float* b2   = (const float*)d_in[9];
    float* out = (float*)d_out;

    int n = in_sizes[0] / 512;   // 100000
    int E = in_sizes[1];         // 3200000

    char* ws = (char*)d_ws;
    size_t off = 0;
    auto alloc = [&](size_t bytes) { size_t o = off; off += (bytes + 255) & ~(size_t)255; return o; };

    int*   counts    = (int*)(ws + alloc((size_t)n * 4));
    int*   row_start = (int*)(ws + alloc((size_t)(n + 1) * 4));
    int*   cursor    = (int*)(ws + alloc((size_t)n * 4));
    int*   scol      = (int*)(ws + alloc((size_t)E * 4));
    float* sval      = (float*)(ws + alloc((size_t)E * 4));
    float* h0        = (float*)(ws + alloc((size_t)n * 256 * 4));
    float* h1        = (float*)(ws + alloc((size_t)n * 256 * 4));
    float* h2        = (float*)(ws + alloc((size_t)n * 64 * 4));
    unsigned short* w1t = (unsigned short*)(ws + alloc((size_t)256 * 512 * 2));
    float* stats     = (float*)(ws + alloc(2048 * 4));
    float* sums1  = stats;
    float* sumsq1 = stats + 256;
    float* sums2  = stats + 512;
    float* sumsq2 = stats + 576;
    float* scale1 = stats + 640;
    float* shift1 = stats + 896;
    float* scale2 = stats + 1152;
    float* shift2 = stats + 1216;

    float invN = 1.0f / (float)n;

    // 1. zero counts + stat accumulators
    zero_kernel<<<dim3((n + 255) / 256), dim3(256), 0, stream>>>(counts, stats, n, 640);
    // 2. histogram of rows
    hist_kernel<<<dim3((E + 255) / 256), dim3(256), 0, stream>>>(erow, counts, E);
    // 3. prefix sum -> CSR row_start + cursor
    scan_kernel<<<dim3(1), dim3(1024), 0, stream>>>(counts, row_start, cursor, n);
    // 4. scatter edges into CSR order
    scatter_kernel<<<dim3((E + 255) / 256), dim3(256), 0, stream>>>(erow, ecol, ev, cursor, scol, sval, E);
    // 4b. W1 -> bf16 transposed
    prep_w1_kernel<<<dim3(512), dim3(256), 0, stream>>>(W1, w1t);
    // 5. h0 = x @ W1  (bf16 MFMA)
    gemm1_mfma_kernel<<<dim3(2, (n + 127) / 128), dim3(256), 0, stream>>>(x, w1t, h0, n);
    // 6. h1 = relu(spmm(h0))
    agg1_kernel<<<dim3((n + 3) / 4), dim3(256), 0, stream>>>(h0, row_start, scol, sval, h1, n);
    // 7. BN1 stats
    colstats1_kernel<<<dim3(400), dim3(256), 0, stream>>>(h1, sums1, sumsq1, n, (n + 399) / 400);
    // 8. BN1 params
    bnparams_kernel<<<dim3(1), dim3(256), 0, stream>>>(sums1, sumsq1, g1, b1, scale1, shift1, 256, invN);
    // 9. h2 = relu(bn1(h1)) @ W2
    gemm2_kernel<<<dim3((n + 127) / 128), dim3(256), 0, stream>>>(h1, W2, scale1, shift1, h2, n);
    // 10. out_pre = relu(spmm(h2))  (written into d_out)
    agg2_kernel<<<dim3((n + 3) / 4), dim3(256), 0, stream>>>(h2, row_start, scol, sval, out, n);
    // 11. BN2 stats
    colstats2_kernel<<<dim3(200), dim3(256), 0, stream>>>(out, sums2, sumsq2, n, (n + 199) / 200);
    // 12. BN2 params
    bnparams_kernel<<<dim3(1), dim3(64), 0, stream>>>(sums2, sumsq2, g2, b2, scale2, shift2, 64, invN);
    // 13. in-place BN apply on d_out
    bnapply_kernel<<<dim3((n * 64 + 255) / 256), dim3(256), 0, stream>>>(out, scale2, shift2, n * 64);

    (void)n_in; (void)out_size; (void)ws_size;
}

// Round 3
// 1456.923 us; speedup vs baseline: 1.5751x; 1.1622x over previous
//
#include <hip/hip_runtime.h>

#define EPS 1e-5f

typedef __attribute__((ext_vector_type(8))) short short8;
typedef __attribute__((ext_vector_type(4))) float floatx4;
typedef __attribute__((ext_vector_type(4))) unsigned short ushortx4;
typedef __attribute__((ext_vector_type(2))) unsigned short ushortx2;

__device__ __forceinline__ unsigned short f2bf(float f) {
    unsigned u = __float_as_uint(f);
    unsigned r = (u + 0x7FFFu + ((u >> 16) & 1u)) >> 16;
    return (unsigned short)r;
}
__device__ __forceinline__ float bf2f(unsigned short h) {
    return __uint_as_float((unsigned)h << 16);
}

// ---------------------------------------------------------------- utilities
__global__ void zero_kernel(int* __restrict__ counts, float* __restrict__ stats,
                            int n_counts, int n_stats) {
    int i = blockIdx.x * 256 + threadIdx.x;
    if (i < n_counts) counts[i] = 0;
    if (i < n_stats)  stats[i]  = 0.0f;
}

__global__ void hist_kernel(const int* __restrict__ erow, int* __restrict__ counts, int E) {
    int e = blockIdx.x * 256 + threadIdx.x;
    if (e < E) atomicAdd(&counts[erow[e]], 1);
}

// single-block exclusive scan over counts -> row_start[n+1], cursor[n]
__global__ __launch_bounds__(1024) void scan_kernel(const int* __restrict__ counts,
                                                    int* __restrict__ row_start,
                                                    int* __restrict__ cursor, int n) {
    __shared__ int lds[1024];
    int t = threadIdx.x;
    int per = (n + 1023) >> 10;
    int s0 = t * per;
    int s1 = min(s0 + per, n);
    int sum = 0;
    for (int i = s0; i < s1; i++) sum += counts[i];
    lds[t] = sum;
    __syncthreads();
    for (int off = 1; off < 1024; off <<= 1) {
        int v = (t >= off) ? lds[t - off] : 0;
        __syncthreads();
        lds[t] += v;
        __syncthreads();
    }
    int run = lds[t] - sum;  // exclusive prefix
    for (int i = s0; i < s1; i++) {
        row_start[i] = run;
        cursor[i]    = run;
        run += counts[i];
    }
    if (t == 0) row_start[n] = lds[1023];
}

__global__ void scatter_kernel(const int* __restrict__ erow, const int* __restrict__ ecol,
                               const float* __restrict__ eval_, int* __restrict__ cursor,
                               int2* __restrict__ edges, int E) {
    int e = blockIdx.x * 256 + threadIdx.x;
    if (e < E) {
        int r = erow[e];
        int p = atomicAdd(&cursor[r], 1);
        edges[p] = make_int2(ecol[e], __float_as_int(eval_[e]));
    }
}

// ---------------------------------------------------------------- W1 -> split bf16 transposed [256][512]
__global__ void prep_w1_kernel(const float* __restrict__ W1,
                               unsigned short* __restrict__ Bhi,
                               unsigned short* __restrict__ Blo) {
    int idx = blockIdx.x * 256 + threadIdx.x;   // 131072 total
    int nn = idx >> 9, k = idx & 511;
    float w = W1[(size_t)k * 256 + nn];
    unsigned short hi = f2bf(w);
    float rem = w - bf2f(hi);
    Bhi[idx] = hi;
    Blo[idx] = f2bf(rem);
}

// ---------------------------------------------------------------- GEMM1 (split-bf16 MFMA, ~fp32 exact):
// h0[M,256](bf16) = A[M,512](fp32) @ W1.  acc += ah*bh + al*bh + ah*bl.
// Block 256 thr = 4 waves 2x2; block tile 128x128; wave tile 64x64 = 4x4 MFMA 16x16x32.
__global__ __launch_bounds__(256) void gemm1_mfma_kernel(const float* __restrict__ A,
                                                         const unsigned short* __restrict__ Bhi,
                                                         const unsigned short* __restrict__ Blo,
                                                         unsigned short* __restrict__ H0, int M) {
    __shared__ unsigned short AsH[128][32];
    __shared__ unsigned short AsL[128][32];
    __shared__ unsigned short BsH[128][32];
    __shared__ unsigned short BsL[128][32];
    int tid  = threadIdx.x;
    int lane = tid & 63, w = tid >> 6;
    int wm = w & 1, wn = w >> 1;
    int rowBase = blockIdx.y * 128;
    int colBase = blockIdx.x * 128;

    floatx4 acc[4][4];
#pragma unroll
    for (int i = 0; i < 4; i++)
#pragma unroll
        for (int j = 0; j < 4; j++)
#pragma unroll
            for (int r = 0; r < 4; r++) acc[i][j][r] = 0.0f;

    int r    = tid >> 1;        // 0..127 staging row
    int half = tid & 1;         // which 16-element k-chunk
    bool aval = (rowBase + r) < M;
    const float* aptr = A + (size_t)(rowBase + r) * 512 + half * 16;
    const unsigned short* bhptr = Bhi + (size_t)(colBase + r) * 512 + half * 16;
    const unsigned short* blptr = Blo + (size_t)(colBase + r) * 512 + half * 16;

    int cl = lane & 15, quad = lane >> 4;
    int q8 = quad * 8;

    for (int k0 = 0; k0 < 512; k0 += 32) {
        // ---- stage A (fp32 -> bf16 hi+lo) : 16 floats per thread
        float f[16];
        if (aval) {
            *(float4*)&f[0]  = *(const float4*)(aptr + k0);
            *(float4*)&f[4]  = *(const float4*)(aptr + k0 + 4);
            *(float4*)&f[8]  = *(const float4*)(aptr + k0 + 8);
            *(float4*)&f[12] = *(const float4*)(aptr + k0 + 12);
        } else {
#pragma unroll
            for (int t = 0; t < 16; t++) f[t] = 0.0f;
        }
        union { unsigned short s[16]; uint4 q[2]; } ph, pl;
#pragma unroll
        for (int t = 0; t < 16; t++) {
            unsigned short hi = f2bf(f[t]);
            ph.s[t] = hi;
            pl.s[t] = f2bf(f[t] - bf2f(hi));
        }
        *(uint4*)&AsH[r][half * 16]     = ph.q[0];
        *(uint4*)&AsH[r][half * 16 + 8] = ph.q[1];
        *(uint4*)&AsL[r][half * 16]     = pl.q[0];
        *(uint4*)&AsL[r][half * 16 + 8] = pl.q[1];
        // ---- stage B (pre-split bf16, [n][k])
        *(uint4*)&BsH[r][half * 16]     = *(const uint4*)(bhptr + k0);
        *(uint4*)&BsH[r][half * 16 + 8] = *(const uint4*)(bhptr + k0 + 8);
        *(uint4*)&BsL[r][half * 16]     = *(const uint4*)(blptr + k0);
        *(uint4*)&BsL[r][half * 16 + 8] = *(const uint4*)(blptr + k0 + 8);
        __syncthreads();

        short8 ah[4], al[4], bh[4], bl[4];
#pragma unroll
        for (int mt = 0; mt < 4; mt++) {
            ah[mt] = *(short8*)&AsH[wm * 64 + mt * 16 + cl][q8];
            al[mt] = *(short8*)&AsL[wm * 64 + mt * 16 + cl][q8];
        }
#pragma unroll
        for (int nt = 0; nt < 4; nt++) {
            bh[nt] = *(short8*)&BsH[wn * 64 + nt * 16 + cl][q8];
            bl[nt] = *(short8*)&BsL[wn * 64 + nt * 16 + cl][q8];
        }
#pragma unroll
        for (int mt = 0; mt < 4; mt++)
#pragma unroll
            for (int nt = 0; nt < 4; nt++) {
                acc[mt][nt] = __builtin_amdgcn_mfma_f32_16x16x32_bf16(ah[mt], bh[nt], acc[mt][nt], 0, 0, 0);
                acc[mt][nt] = __builtin_amdgcn_mfma_f32_16x16x32_bf16(al[mt], bh[nt], acc[mt][nt], 0, 0, 0);
                acc[mt][nt] = __builtin_amdgcn_mfma_f32_16x16x32_bf16(ah[mt], bl[nt], acc[mt][nt], 0, 0, 0);
            }
        __syncthreads();
    }

    // epilogue: C/D layout col=lane&15, row=quad*4+reg ; store bf16
#pragma unroll
    for (int mt = 0; mt < 4; mt++) {
#pragma unroll
        for (int reg = 0; reg < 4; reg++) {
            int gr = rowBase + wm * 64 + mt * 16 + quad * 4 + reg;
            if (gr < M) {
#pragma unroll
                for (int nt = 0; nt < 4; nt++) {
                    H0[(size_t)gr * 256 + colBase + wn * 64 + nt * 16 + cl] = f2bf(acc[mt][nt][reg]);
                }
            }
        }
    }
}

// ---------------------------------------------------------------- SpMM1 (F=256): wave per row, bf16 gather
__global__ __launch_bounds__(256) void agg1_kernel(const unsigned short* __restrict__ H0,
                                                   const int* __restrict__ rs,
                                                   const int2* __restrict__ edges,
                                                   float* __restrict__ H1, int n) {
    int w = threadIdx.x >> 6, lane = threadIdx.x & 63;
    int i = blockIdx.x * 4 + w;
    if (i >= n) return;
    int start = rs[i], end = rs[i + 1];
    int fo = lane << 2;
    float4 acc = make_float4(0.f, 0.f, 0.f, 0.f);
    int j = start;
    for (; j + 8 <= end; j += 8) {
        int2 e[8];
        ushortx4 u[8];
#pragma unroll
        for (int t = 0; t < 8; t++) e[t] = edges[j + t];
#pragma unroll
        for (int t = 0; t < 8; t++)
            u[t] = *(const ushortx4*)(H0 + (size_t)e[t].x * 256 + fo);
#pragma unroll
        for (int t = 0; t < 8; t++) {
            float v = __int_as_float(e[t].y);
            acc.x += v * bf2f(u[t].x);
            acc.y += v * bf2f(u[t].y);
            acc.z += v * bf2f(u[t].z);
            acc.w += v * bf2f(u[t].w);
        }
    }
    for (; j < end; j++) {
        int2 e = edges[j];
        float v = __int_as_float(e.y);
        ushortx4 u = *(const ushortx4*)(H0 + (size_t)e.x * 256 + fo);
        acc.x += v * bf2f(u.x);
        acc.y += v * bf2f(u.y);
        acc.z += v * bf2f(u.z);
        acc.w += v * bf2f(u.w);
    }
    float4 o;
    o.x = fmaxf(acc.x, 0.f); o.y = fmaxf(acc.y, 0.f);
    o.z = fmaxf(acc.z, 0.f); o.w = fmaxf(acc.w, 0.f);
    *(float4*)(H1 + (size_t)i * 256 + fo) = o;
}

// ---------------------------------------------------------------- column stats F=256
__global__ __launch_bounds__(256) void colstats1_kernel(const float* __restrict__ H1,
                                                        float* __restrict__ sums,
                                                        float* __restrict__ sumsq,
                                                        int n, int rpb) {
    int tid = threadIdx.x;
    int r0 = blockIdx.x * rpb;
    int r1 = min(r0 + rpb, n);
    float s = 0.f, q = 0.f;
    for (int rr = r0; rr < r1; rr++) {
        float v = H1[(size_t)rr * 256 + tid];
        s += v; q += v * v;
    }
    atomicAdd(&sums[tid], s);
    atomicAdd(&sumsq[tid], q);
}

__global__ void bnparams_kernel(const float* __restrict__ sums, const float* __restrict__ sumsq,
                                const float* __restrict__ gamma, const float* __restrict__ beta,
                                float* __restrict__ scale, float* __restrict__ shift,
                                int C, float invN) {
    int c = threadIdx.x;
    if (c < C) {
        float mean = sums[c] * invN;
        float var  = sumsq[c] * invN - mean * mean;
        float rstd = rsqrtf(var + EPS);
        float sc   = gamma[c] * rstd;
        scale[c] = sc;
        shift[c] = beta[c] - mean * sc;
    }
}

// ---------------------------------------------------------------- GEMM2: relu(bn1(H1)) @ W2 -> bf16
// BM=128, BN=64(full), BK=8, 256 threads, 8x4 microtile (fp32 vector ALU)
__global__ __launch_bounds__(256) void gemm2_kernel(const float* __restrict__ H1,
                                                    const float* __restrict__ W2,
                                                    const float* __restrict__ scale1,
                                                    const float* __restrict__ shift1,
                                                    unsigned short* __restrict__ H2, int M) {
    __shared__ float As[8][129];
    __shared__ float Bs[8][64];
    int tid = threadIdx.x;
    int tx = tid & 15, ty = tid >> 4;
    int rowBase = blockIdx.x * 128;
    float acc[8][4];
#pragma unroll
    for (int i = 0; i < 8; i++)
#pragma unroll
        for (int j = 0; j < 4; j++) acc[i][j] = 0.0f;

    int r   = tid >> 1;
    int kq  = (tid & 1) * 4;
    int bkk = tid >> 6;       // 0..3
    int bcol = tid & 63;

    for (int k0 = 0; k0 < 256; k0 += 8) {
        float4 a4 = make_float4(0.f, 0.f, 0.f, 0.f);
        int arow = rowBase + r;
        if (arow < M) a4 = *(const float4*)(H1 + (size_t)arow * 256 + k0 + kq);
        float av[4] = {a4.x, a4.y, a4.z, a4.w};
#pragma unroll
        for (int jj = 0; jj < 4; jj++) {
            int kk = k0 + kq + jj;
            float t = av[jj] * scale1[kk] + shift1[kk];
            As[kq + jj][r] = fmaxf(t, 0.0f);
        }
        Bs[bkk][bcol]     = W2[(size_t)(k0 + bkk) * 64 + bcol];
        Bs[bkk + 4][bcol] = W2[(size_t)(k0 + bkk + 4) * 64 + bcol];
        __syncthreads();
#pragma unroll
        for (int k = 0; k < 8; k++) {
            float ra[8], rb[4];
#pragma unroll
            for (int i = 0; i < 8; i++) ra[i] = As[k][ty * 8 + i];
#pragma unroll
            for (int j = 0; j < 4; j++) rb[j] = Bs[k][tx * 4 + j];
#pragma unroll
            for (int i = 0; i < 8; i++)
#pragma unroll
                for (int j = 0; j < 4; j++) acc[i][j] += ra[i] * rb[j];
        }
        __syncthreads();
    }
#pragma unroll
    for (int i = 0; i < 8; i++) {
        int crow = rowBase + ty * 8 + i;
        if (crow < M) {
            ushortx4 o;
            o.x = f2bf(acc[i][0]); o.y = f2bf(acc[i][1]);
            o.z = f2bf(acc[i][2]); o.w = f2bf(acc[i][3]);
            *(ushortx4*)(H2 + (size_t)crow * 64 + tx * 4) = o;
        }
    }
}

// ---------------------------------------------------------------- SpMM2 (F=64): half-wave per row, bf16 gather
__global__ __launch_bounds__(256) void agg2_kernel(const unsigned short* __restrict__ H2,
                                                   const int* __restrict__ rs,
                                                   const int2* __restrict__ edges,
                                                   float* __restrict__ H3, int n) {
    int w = threadIdx.x >> 6, lane = threadIdx.x & 63;
    int half = lane >> 5, sub = lane & 31;
    int i = blockIdx.x * 8 + w * 2 + half;
    if (i >= n) return;
    int start = rs[i], end = rs[i + 1];
    int fo = sub << 1;
    float accx = 0.f, accy = 0.f;
    int j = start;
    for (; j + 4 <= end; j += 4) {
        int2 e[4];
        ushortx2 u[4];
#pragma unroll
        for (int t = 0; t < 4; t++) e[t] = edges[j + t];
#pragma unroll
        for (int t = 0; t < 4; t++)
            u[t] = *(const ushortx2*)(H2 + (size_t)e[t].x * 64 + fo);
#pragma unroll
        for (int t = 0; t < 4; t++) {
            float v = __int_as_float(e[t].y);
            accx += v * bf2f(u[t].x);
            accy += v * bf2f(u[t].y);
        }
    }
    for (; j < end; j++) {
        int2 e = edges[j];
        float v = __int_as_float(e.y);
        ushortx2 u = *(const ushortx2*)(H2 + (size_t)e.x * 64 + fo);
        accx += v * bf2f(u.x);
        accy += v * bf2f(u.y);
    }
    float2 o;
    o.x = fmaxf(accx, 0.f);
    o.y = fmaxf(accy, 0.f);
    *(float2*)(H3 + (size_t)i * 64 + fo) = o;
}

// ---------------------------------------------------------------- column stats F=64
__global__ __launch_bounds__(256) void colstats2_kernel(const float* __restrict__ H3,
                                                        float* __restrict__ sums,
                                                        float* __restrict__ sumsq,
                                                        int n, int rpb) {
    int c = threadIdx.x & 63, rsub = threadIdx.x >> 6;
    int base = blockIdx.x * rpb;
    int r1 = min(base + rpb, n);
    float s = 0.f, q = 0.f;
    for (int rr = base + rsub; rr < r1; rr += 4) {
        float v = H3[(size_t)rr * 64 + c];
        s += v; q += v * v;
    }
    atomicAdd(&sums[c], s);
    atomicAdd(&sumsq[c], q);
}

__global__ void bnapply_kernel(float* __restrict__ out, const float* __restrict__ scale,
                               const float* __restrict__ shift, int total) {
    int idx = blockIdx.x * 256 + threadIdx.x;
    if (idx < total) {
        int c = idx & 63;
        out[idx] = out[idx] * scale[c] + shift[c];
    }
}

// ---------------------------------------------------------------- launch
extern "C" void kernel_launch(void* const* d_in, const int* in_sizes, int n_in,
                              void* d_out, int out_size, void* d_ws, size_t ws_size,
                              hipStream_t stream) {
    const float* x    = (const float*)d_in[0];
    const int*   erow = (const int*)d_in[1];
    const int*   ecol = (const int*)d_in[2];
    const float* ev   = (const float*)d_in[3];
    const float* W1   = (const float*)d_in[4];
    const float* g1   = (const float*)d_in[5];
    const float* b1   = (const float*)d_in[6];
    const float* W2   = (const float*)d_in[7];
    const float* g2   = (const float*)d_in[8];
    const float* b2   = (const float*)d_in[9];
    float* out = (float*)d_out;

    int n = in_sizes[0] / 512;   // 100000
    int E = in_sizes[1];         // 3200000

    char* ws = (char*)d_ws;
    size_t off = 0;
    auto alloc = [&](size_t bytes) { size_t o = off; off += (bytes + 255) & ~(size_t)255; return o; };

    int*   counts    = (int*)(ws + alloc((size_t)n * 4));
    int*   row_start = (int*)(ws + alloc((size_t)(n + 1) * 4));
    int*   cursor    = (int*)(ws + alloc((size_t)n * 4));
    int2*  edges     = (int2*)(ws + alloc((size_t)E * 8));
    unsigned short* h0 = (unsigned short*)(ws + alloc((size_t)n * 256 * 2));
    float* h1        = (float*)(ws + alloc((size_t)n * 256 * 4));
    unsigned short* h2 = (unsigned short*)(ws + alloc((size_t)n * 64 * 2));
    unsigned short* w1hi = (unsigned short*)(ws + alloc((size_t)256 * 512 * 2));
    unsigned short* w1lo = (unsigned short*)(ws + alloc((size_t)256 * 512 * 2));
    float* stats     = (float*)(ws + alloc(2048 * 4));
    float* sums1  = stats;
    float* sumsq1 = stats + 256;
    float* sums2  = stats + 512;
    float* sumsq2 = stats + 576;
    float* scale1 = stats + 640;
    float* shift1 = stats + 896;
    float* scale2 = stats + 1152;
    float* shift2 = stats + 1216;

    float invN = 1.0f / (float)n;

    // 1. zero counts + stat accumulators
    zero_kernel<<<dim3((n + 255) / 256), dim3(256), 0, stream>>>(counts, stats, n, 640);
    // 2. histogram of rows
    hist_kernel<<<dim3((E + 255) / 256), dim3(256), 0, stream>>>(erow, counts, E);
    // 3. prefix sum -> CSR row_start + cursor
    scan_kernel<<<dim3(1), dim3(1024), 0, stream>>>(counts, row_start, cursor, n);
    // 4. scatter edges into CSR order (packed int2)
    scatter_kernel<<<dim3((E + 255) / 256), dim3(256), 0, stream>>>(erow, ecol, ev, cursor, edges, E);
    // 4b. W1 -> split bf16 transposed
    prep_w1_kernel<<<dim3(512), dim3(256), 0, stream>>>(W1, w1hi, w1lo);
    // 5. h0(bf16) = x @ W1  (split-bf16 MFMA, ~fp32 accurate)
    gemm1_mfma_kernel<<<dim3(2, (n + 127) / 128), dim3(256), 0, stream>>>(x, w1hi, w1lo, h0, n);
    // 6. h1 = relu(spmm(h0))  (bf16 gather, fp32 accum)
    agg1_kernel<<<dim3((n + 3) / 4), dim3(256), 0, stream>>>(h0, row_start, edges, h1, n);
    // 7. BN1 stats
    colstats1_kernel<<<dim3(400), dim3(256), 0, stream>>>(h1, sums1, sumsq1, n, (n + 399) / 400);
    // 8. BN1 params
    bnparams_kernel<<<dim3(1), dim3(256), 0, stream>>>(sums1, sumsq1, g1, b1, scale1, shift1, 256, invN);
    // 9. h2(bf16) = relu(bn1(h1)) @ W2  (fp32 vector ALU, exact)
    gemm2_kernel<<<dim3((n + 127) / 128), dim3(256), 0, stream>>>(h1, W2, scale1, shift1, h2, n);
    // 10. out_pre = relu(spmm(h2))  (bf16 gather, written into d_out)
    agg2_kernel<<<dim3((n + 7) / 8), dim3(256), 0, stream>>>(h2, row_start, edges, out, n);
    // 11. BN2 stats
    colstats2_kernel<<<dim3(200), dim3(256), 0, stream>>>(out, sums2, sumsq2, n, (n + 199) / 200);
    // 12. BN2 params
    bnparams_kernel<<<dim3(1), dim3(64), 0, stream>>>(sums2, sumsq2, g2, b2, scale2, shift2, 64, invN);
    // 13. in-place BN apply on d_out
    bnapply_kernel<<<dim3((n * 64 + 255) / 256), dim3(256), 0, stream>>>(out, scale2, shift2, n * 64);

    (void)n_in; (void)out_size; (void)ws_size;
}

// Round 4
// 1093.233 us; speedup vs baseline: 2.0991x; 1.3327x over previous
//
#include <hip/hip_runtime.h>

#define EPS 1e-5f

typedef __attribute__((ext_vector_type(8))) short short8;
typedef __attribute__((ext_vector_type(4))) float floatx4;
typedef __attribute__((ext_vector_type(4))) unsigned short ushortx4;
typedef __attribute__((ext_vector_type(2))) unsigned short ushortx2;

__device__ __forceinline__ unsigned short f2bf(float f) {
    unsigned u = __float_as_uint(f);
    unsigned r = (u + 0x7FFFu + ((u >> 16) & 1u)) >> 16;
    return (unsigned short)r;
}
__device__ __forceinline__ float bf2f(unsigned short h) {
    return __uint_as_float((unsigned)h << 16);
}

// ---------------------------------------------------------------- utilities
__global__ void zero_kernel(int* __restrict__ hist2, float* __restrict__ stats,
                            int n_hist, int n_stats) {
    int i = blockIdx.x * 256 + threadIdx.x;
    if (i < n_hist)  hist2[i] = 0;
    if (i < n_stats) stats[i] = 0.0f;
}

// per-chunk LDS histogram of buckets (row>>7), flushed to hist2[b*8+g], g=blockIdx&7
__global__ __launch_bounds__(256) void bucket_hist_kernel(const int* __restrict__ erow,
                                                          int* __restrict__ hist2,
                                                          int E, int chunk, int nb) {
    __shared__ int cnt[1024];
    int g = blockIdx.x & 7;
    for (int i = threadIdx.x; i < nb; i += 256) cnt[i] = 0;
    __syncthreads();
    int base = blockIdx.x * chunk;
    int end = min(base + chunk, E);
    for (int j = base + threadIdx.x; j < end; j += 256)
        atomicAdd(&cnt[erow[j] >> 7], 1);
    __syncthreads();
    for (int i = threadIdx.x; i < nb; i += 256) {
        int c = cnt[i];
        if (c) atomicAdd(&hist2[i * 8 + g], c);
    }
}

// single-block exclusive scan over hist2[nb*8] -> cursor2 (working copies) + bucket_start
__global__ __launch_bounds__(1024) void bucket_scan_kernel(const int* __restrict__ hist2,
                                                           int* __restrict__ cursor2,
                                                           int* __restrict__ bucket_start,
                                                           int* __restrict__ row_start,
                                                           int nb, int n, int E) {
    __shared__ int lds[1024];
    int t = threadIdx.x;
    int total = nb * 8;
    int per = (total + 1023) >> 10;
    int s0 = t * per, s1 = min(s0 + per, total);
    int sum = 0;
    for (int i = s0; i < s1; i++) sum += hist2[i];
    lds[t] = sum;
    __syncthreads();
    for (int off = 1; off < 1024; off <<= 1) {
        int v = (t >= off) ? lds[t - off] : 0;
        __syncthreads();
        lds[t] += v;
        __syncthreads();
    }
    int run = lds[t] - sum;  // exclusive prefix
    for (int i = s0; i < s1; i++) {
        cursor2[i] = run;
        if ((i & 7) == 0) bucket_start[i >> 3] = run;
        run += hist2[i];
    }
    if (t == 0) { bucket_start[nb] = E; row_start[n] = E; }
}

// pass 1: append edges into per-(bucket, group) sub-regions; key packs localrow in bits 17..23
__global__ __launch_bounds__(256) void pass1_scatter_kernel(const int* __restrict__ erow,
                                                            const int* __restrict__ ecol,
                                                            const float* __restrict__ ev,
                                                            int* __restrict__ cursor2,
                                                            int2* __restrict__ tmp,
                                                            int E, int chunk) {
    int g = blockIdx.x & 7;
    int base = blockIdx.x * chunk;
    int end = min(base + chunk, E);
    for (int j = base + threadIdx.x; j < end; j += 256) {
        int r = erow[j];
        int b = r >> 7, lr = r & 127;
        int key = ecol[j] | (lr << 17);
        int p = atomicAdd(&cursor2[b * 8 + g], 1);
        tmp[p] = make_int2(key, __float_as_int(ev[j]));
    }
}

// pass 2: one block per bucket. LDS row counts -> scan -> row_start + exact CSR placement.
__global__ __launch_bounds__(256) void pass2_kernel(const int2* __restrict__ tmp,
                                                    const int* __restrict__ bucket_start,
                                                    int* __restrict__ row_start,
                                                    int2* __restrict__ edges, int n) {
    __shared__ int cnt[128], scn[128], cur[128];
    int b = blockIdx.x, t = threadIdx.x;
    int bstart = bucket_start[b], bend = bucket_start[b + 1];
    if (t < 128) cnt[t] = 0;
    __syncthreads();
    for (int j = bstart + t; j < bend; j += 256)
        atomicAdd(&cnt[((unsigned)tmp[j].x) >> 17], 1);
    __syncthreads();
    if (t < 128) scn[t] = cnt[t];
    __syncthreads();
#pragma unroll
    for (int off = 1; off < 128; off <<= 1) {
        int v = 0;
        if (t < 128 && t >= off) v = scn[t - off];
        __syncthreads();
        if (t < 128) scn[t] += v;
        __syncthreads();
    }
    if (t < 128) {
        int pref = scn[t] - cnt[t];   // exclusive prefix within bucket
        cur[t] = pref;
        int r = b * 128 + t;
        if (r <= n) row_start[r] = bstart + pref;
    }
    __syncthreads();
    for (int j = bstart + t; j < bend; j += 256) {
        int2 e = tmp[j];
        int lr = ((unsigned)e.x) >> 17;
        int pos = atomicAdd(&cur[lr], 1);
        edges[bstart + pos] = make_int2(e.x & 0x1FFFF, e.y);
    }
}

// ---------------------------------------------------------------- W1 -> split bf16 transposed [256][512]
__global__ void prep_w1_kernel(const float* __restrict__ W1,
                               unsigned short* __restrict__ Bhi,
                               unsigned short* __restrict__ Blo) {
    int idx = blockIdx.x * 256 + threadIdx.x;   // 131072 total
    int nn = idx >> 9, k = idx & 511;
    float w = W1[(size_t)k * 256 + nn];
    unsigned short hi = f2bf(w);
    float rem = w - bf2f(hi);
    Bhi[idx] = hi;
    Blo[idx] = f2bf(rem);
}

// ---------------------------------------------------------------- GEMM1 (split-bf16 MFMA, ~fp32 exact):
// h0[M,256](bf16) = A[M,512](fp32) @ W1.  acc += ah*bh + al*bh + ah*bl.
__global__ __launch_bounds__(256) void gemm1_mfma_kernel(const float* __restrict__ A,
                                                         const unsigned short* __restrict__ Bhi,
                                                         const unsigned short* __restrict__ Blo,
                                                         unsigned short* __restrict__ H0, int M) {
    __shared__ unsigned short AsH[128][32];
    __shared__ unsigned short AsL[128][32];
    __shared__ unsigned short BsH[128][32];
    __shared__ unsigned short BsL[128][32];
    int tid  = threadIdx.x;
    int lane = tid & 63, w = tid >> 6;
    int wm = w & 1, wn = w >> 1;
    int rowBase = blockIdx.y * 128;
    int colBase = blockIdx.x * 128;

    floatx4 acc[4][4];
#pragma unroll
    for (int i = 0; i < 4; i++)
#pragma unroll
        for (int j = 0; j < 4; j++)
#pragma unroll
            for (int r = 0; r < 4; r++) acc[i][j][r] = 0.0f;

    int r    = tid >> 1;
    int half = tid & 1;
    bool aval = (rowBase + r) < M;
    const float* aptr = A + (size_t)(rowBase + r) * 512 + half * 16;
    const unsigned short* bhptr = Bhi + (size_t)(colBase + r) * 512 + half * 16;
    const unsigned short* blptr = Blo + (size_t)(colBase + r) * 512 + half * 16;

    int cl = lane & 15, quad = lane >> 4;
    int q8 = quad * 8;

    for (int k0 = 0; k0 < 512; k0 += 32) {
        float f[16];
        if (aval) {
            *(float4*)&f[0]  = *(const float4*)(aptr + k0);
            *(float4*)&f[4]  = *(const float4*)(aptr + k0 + 4);
            *(float4*)&f[8]  = *(const float4*)(aptr + k0 + 8);
            *(float4*)&f[12] = *(const float4*)(aptr + k0 + 12);
        } else {
#pragma unroll
            for (int t = 0; t < 16; t++) f[t] = 0.0f;
        }
        union { unsigned short s[16]; uint4 q[2]; } ph, pl;
#pragma unroll
        for (int t = 0; t < 16; t++) {
            unsigned short hi = f2bf(f[t]);
            ph.s[t] = hi;
            pl.s[t] = f2bf(f[t] - bf2f(hi));
        }
        *(uint4*)&AsH[r][half * 16]     = ph.q[0];
        *(uint4*)&AsH[r][half * 16 + 8] = ph.q[1];
        *(uint4*)&AsL[r][half * 16]     = pl.q[0];
        *(uint4*)&AsL[r][half * 16 + 8] = pl.q[1];
        *(uint4*)&BsH[r][half * 16]     = *(const uint4*)(bhptr + k0);
        *(uint4*)&BsH[r][half * 16 + 8] = *(const uint4*)(bhptr + k0 + 8);
        *(uint4*)&BsL[r][half * 16]     = *(const uint4*)(blptr + k0);
        *(uint4*)&BsL[r][half * 16 + 8] = *(const uint4*)(blptr + k0 + 8);
        __syncthreads();

        short8 ah[4], al[4], bh[4], bl[4];
#pragma unroll
        for (int mt = 0; mt < 4; mt++) {
            ah[mt] = *(short8*)&AsH[wm * 64 + mt * 16 + cl][q8];
            al[mt] = *(short8*)&AsL[wm * 64 + mt * 16 + cl][q8];
        }
#pragma unroll
        for (int nt = 0; nt < 4; nt++) {
            bh[nt] = *(short8*)&BsH[wn * 64 + nt * 16 + cl][q8];
            bl[nt] = *(short8*)&BsL[wn * 64 + nt * 16 + cl][q8];
        }
#pragma unroll
        for (int mt = 0; mt < 4; mt++)
#pragma unroll
            for (int nt = 0; nt < 4; nt++) {
                acc[mt][nt] = __builtin_amdgcn_mfma_f32_16x16x32_bf16(ah[mt], bh[nt], acc[mt][nt], 0, 0, 0);
                acc[mt][nt] = __builtin_amdgcn_mfma_f32_16x16x32_bf16(al[mt], bh[nt], acc[mt][nt], 0, 0, 0);
                acc[mt][nt] = __builtin_amdgcn_mfma_f32_16x16x32_bf16(ah[mt], bl[nt], acc[mt][nt], 0, 0, 0);
            }
        __syncthreads();
    }

#pragma unroll
    for (int mt = 0; mt < 4; mt++) {
#pragma unroll
        for (int reg = 0; reg < 4; reg++) {
            int gr = rowBase + wm * 64 + mt * 16 + quad * 4 + reg;
            if (gr < M) {
#pragma unroll
                for (int nt = 0; nt < 4; nt++) {
                    H0[(size_t)gr * 256 + colBase + wn * 64 + nt * 16 + cl] = f2bf(acc[mt][nt][reg]);
                }
            }
        }
    }
}

// ---------------------------------------------------------------- SpMM1 (F=256): wave per row, bf16 gather
__global__ __launch_bounds__(256) void agg1_kernel(const unsigned short* __restrict__ H0,
                                                   const int* __restrict__ rs,
                                                   const int2* __restrict__ edges,
                                                   float* __restrict__ H1, int n) {
    int w = threadIdx.x >> 6, lane = threadIdx.x & 63;
    int i = blockIdx.x * 4 + w;
    if (i >= n) return;
    int start = rs[i], end = rs[i + 1];
    int fo = lane << 2;
    float4 acc = make_float4(0.f, 0.f, 0.f, 0.f);
    int j = start;
    for (; j + 8 <= end; j += 8) {
        int2 e[8];
        ushortx4 u[8];
#pragma unroll
        for (int t = 0; t < 8; t++) e[t] = edges[j + t];
#pragma unroll
        for (int t = 0; t < 8; t++)
            u[t] = *(const ushortx4*)(H0 + (size_t)e[t].x * 256 + fo);
#pragma unroll
        for (int t = 0; t < 8; t++) {
            float v = __int_as_float(e[t].y);
            acc.x += v * bf2f(u[t].x);
            acc.y += v * bf2f(u[t].y);
            acc.z += v * bf2f(u[t].z);
            acc.w += v * bf2f(u[t].w);
        }
    }
    for (; j < end; j++) {
        int2 e = edges[j];
        float v = __int_as_float(e.y);
        ushortx4 u = *(const ushortx4*)(H0 + (size_t)e.x * 256 + fo);
        acc.x += v * bf2f(u.x);
        acc.y += v * bf2f(u.y);
        acc.z += v * bf2f(u.z);
        acc.w += v * bf2f(u.w);
    }
    float4 o;
    o.x = fmaxf(acc.x, 0.f); o.y = fmaxf(acc.y, 0.f);
    o.z = fmaxf(acc.z, 0.f); o.w = fmaxf(acc.w, 0.f);
    *(float4*)(H1 + (size_t)i * 256 + fo) = o;
}

// ---------------------------------------------------------------- column stats F=256
__global__ __launch_bounds__(256) void colstats1_kernel(const float* __restrict__ H1,
                                                        float* __restrict__ sums,
                                                        float* __restrict__ sumsq,
                                                        int n, int rpb) {
    int tid = threadIdx.x;
    int r0 = blockIdx.x * rpb;
    int r1 = min(r0 + rpb, n);
    float s = 0.f, q = 0.f;
    for (int rr = r0; rr < r1; rr++) {
        float v = H1[(size_t)rr * 256 + tid];
        s += v; q += v * v;
    }
    atomicAdd(&sums[tid], s);
    atomicAdd(&sumsq[tid], q);
}

__global__ void bnparams_kernel(const float* __restrict__ sums, const float* __restrict__ sumsq,
                                const float* __restrict__ gamma, const float* __restrict__ beta,
                                float* __restrict__ scale, float* __restrict__ shift,
                                int C, float invN) {
    int c = threadIdx.x;
    if (c < C) {
        float mean = sums[c] * invN;
        float var  = sumsq[c] * invN - mean * mean;
        float rstd = rsqrtf(var + EPS);
        float sc   = gamma[c] * rstd;
        scale[c] = sc;
        shift[c] = beta[c] - mean * sc;
    }
}

// ---------------------------------------------------------------- GEMM2: relu(bn1(H1)) @ W2 -> bf16
__global__ __launch_bounds__(256) void gemm2_kernel(const float* __restrict__ H1,
                                                    const float* __restrict__ W2,
                                                    const float* __restrict__ scale1,
                                                    const float* __restrict__ shift1,
                                                    unsigned short* __restrict__ H2, int M) {
    __shared__ float As[8][129];
    __shared__ float Bs[8][64];
    int tid = threadIdx.x;
    int tx = tid & 15, ty = tid >> 4;
    int rowBase = blockIdx.x * 128;
    float acc[8][4];
#pragma unroll
    for (int i = 0; i < 8; i++)
#pragma unroll
        for (int j = 0; j < 4; j++) acc[i][j] = 0.0f;

    int r   = tid >> 1;
    int kq  = (tid & 1) * 4;
    int bkk = tid >> 6;
    int bcol = tid & 63;

    for (int k0 = 0; k0 < 256; k0 += 8) {
        float4 a4 = make_float4(0.f, 0.f, 0.f, 0.f);
        int arow = rowBase + r;
        if (arow < M) a4 = *(const float4*)(H1 + (size_t)arow * 256 + k0 + kq);
        float av[4] = {a4.x, a4.y, a4.z, a4.w};
#pragma unroll
        for (int jj = 0; jj < 4; jj++) {
            int kk = k0 + kq + jj;
            float t = av[jj] * scale1[kk] + shift1[kk];
            As[kq + jj][r] = fmaxf(t, 0.0f);
        }
        Bs[bkk][bcol]     = W2[(size_t)(k0 + bkk) * 64 + bcol];
        Bs[bkk + 4][bcol] = W2[(size_t)(k0 + bkk + 4) * 64 + bcol];
        __syncthreads();
#pragma unroll
        for (int k = 0; k < 8; k++) {
            float ra[8], rb[4];
#pragma unroll
            for (int i = 0; i < 8; i++) ra[i] = As[k][ty * 8 + i];
#pragma unroll
            for (int j = 0; j < 4; j++) rb[j] = Bs[k][tx * 4 + j];
#pragma unroll
            for (int i = 0; i < 8; i++)
#pragma unroll
                for (int j = 0; j < 4; j++) acc[i][j] += ra[i] * rb[j];
        }
        __syncthreads();
    }
#pragma unroll
    for (int i = 0; i < 8; i++) {
        int crow = rowBase + ty * 8 + i;
        if (crow < M) {
            ushortx4 o;
            o.x = f2bf(acc[i][0]); o.y = f2bf(acc[i][1]);
            o.z = f2bf(acc[i][2]); o.w = f2bf(acc[i][3]);
            *(ushortx4*)(H2 + (size_t)crow * 64 + tx * 4) = o;
        }
    }
}

// ---------------------------------------------------------------- SpMM2 (F=64): half-wave per row, bf16 gather
__global__ __launch_bounds__(256) void agg2_kernel(const unsigned short* __restrict__ H2,
                                                   const int* __restrict__ rs,
                                                   const int2* __restrict__ edges,
                                                   float* __restrict__ H3, int n) {
    int w = threadIdx.x >> 6, lane = threadIdx.x & 63;
    int half = lane >> 5, sub = lane & 31;
    int i = blockIdx.x * 8 + w * 2 + half;
    if (i >= n) return;
    int start = rs[i], end = rs[i + 1];
    int fo = sub << 1;
    float accx = 0.f, accy = 0.f;
    int j = start;
    for (; j + 4 <= end; j += 4) {
        int2 e[4];
        ushortx2 u[4];
#pragma unroll
        for (int t = 0; t < 4; t++) e[t] = edges[j + t];
#pragma unroll
        for (int t = 0; t < 4; t++)
            u[t] = *(const ushortx2*)(H2 + (size_t)e[t].x * 64 + fo);
#pragma unroll
        for (int t = 0; t < 4; t++) {
            float v = __int_as_float(e[t].y);
            accx += v * bf2f(u[t].x);
            accy += v * bf2f(u[t].y);
        }
    }
    for (; j < end; j++) {
        int2 e = edges[j];
        float v = __int_as_float(e.y);
        ushortx2 u = *(const ushortx2*)(H2 + (size_t)e.x * 64 + fo);
        accx += v * bf2f(u.x);
        accy += v * bf2f(u.y);
    }
    float2 o;
    o.x = fmaxf(accx, 0.f);
    o.y = fmaxf(accy, 0.f);
    *(float2*)(H3 + (size_t)i * 64 + fo) = o;
}

// ---------------------------------------------------------------- column stats F=64
__global__ __launch_bounds__(256) void colstats2_kernel(const float* __restrict__ H3,
                                                        float* __restrict__ sums,
                                                        float* __restrict__ sumsq,
                                                        int n, int rpb) {
    int c = threadIdx.x & 63, rsub = threadIdx.x >> 6;
    int base = blockIdx.x * rpb;
    int r1 = min(base + rpb, n);
    float s = 0.f, q = 0.f;
    for (int rr = base + rsub; rr < r1; rr += 4) {
        float v = H3[(size_t)rr * 64 + c];
        s += v; q += v * v;
    }
    atomicAdd(&sums[c], s);
    atomicAdd(&sumsq[c], q);
}

__global__ void bnapply_kernel(float* __restrict__ out, const float* __restrict__ scale,
                               const float* __restrict__ shift, int total) {
    int idx = blockIdx.x * 256 + threadIdx.x;
    if (idx < total) {
        int c = idx & 63;
        out[idx] = out[idx] * scale[c] + shift[c];
    }
}

// ---------------------------------------------------------------- launch
extern "C" void kernel_launch(void* const* d_in, const int* in_sizes, int n_in,
                              void* d_out, int out_size, void* d_ws, size_t ws_size,
                              hipStream_t stream) {
    const float* x    = (const float*)d_in[0];
    const int*   erow = (const int*)d_in[1];
    const int*   ecol = (const int*)d_in[2];
    const float* ev   = (const float*)d_in[3];
    const float* W1   = (const float*)d_in[4];
    const float* g1   = (const float*)d_in[5];
    const float* b1   = (const float*)d_in[6];
    const float* W2   = (const float*)d_in[7];
    const float* g2   = (const float*)d_in[8];
    const float* b2   = (const float*)d_in[9];
    float* out = (float*)d_out;

    int n = in_sizes[0] / 512;   // 100000
    int E = in_sizes[1];         // 3200000
    int nb = (n + 127) >> 7;     // 782 buckets of 128 rows
    int chunk = 16384;
    int nchunks = (E + chunk - 1) / chunk;

    char* ws = (char*)d_ws;
    size_t off = 0;
    auto alloc = [&](size_t bytes) { size_t o = off; off += (bytes + 255) & ~(size_t)255; return o; };

    int*   hist2        = (int*)(ws + alloc((size_t)nb * 8 * 4));
    int*   cursor2      = (int*)(ws + alloc((size_t)nb * 8 * 4));
    int*   bucket_start = (int*)(ws + alloc((size_t)(nb + 1) * 4));
    int*   row_start    = (int*)(ws + alloc((size_t)(n + 1) * 4));
    int2*  tmp          = (int2*)(ws + alloc((size_t)E * 8));
    int2*  edges        = (int2*)(ws + alloc((size_t)E * 8));
    unsigned short* h0  = (unsigned short*)(ws + alloc((size_t)n * 256 * 2));
    float* h1           = (float*)(ws + alloc((size_t)n * 256 * 4));
    unsigned short* h2  = (unsigned short*)(ws + alloc((size_t)n * 64 * 2));
    unsigned short* w1hi = (unsigned short*)(ws + alloc((size_t)256 * 512 * 2));
    unsigned short* w1lo = (unsigned short*)(ws + alloc((size_t)256 * 512 * 2));
    float* stats        = (float*)(ws + alloc(2048 * 4));
    float* sums1  = stats;
    float* sumsq1 = stats + 256;
    float* sums2  = stats + 512;
    float* sumsq2 = stats + 576;
    float* scale1 = stats + 640;
    float* shift1 = stats + 896;
    float* scale2 = stats + 1152;
    float* shift2 = stats + 1216;

    float invN = 1.0f / (float)n;

    // 1. zero hist2 + stat accumulators
    zero_kernel<<<dim3((nb * 8 + 255) / 256), dim3(256), 0, stream>>>(hist2, stats, nb * 8, 640);
    // 2. bucketed histogram (LDS-preaggregated)
    bucket_hist_kernel<<<dim3(nchunks), dim3(256), 0, stream>>>(erow, hist2, E, chunk, nb);
    // 3. scan -> per-(bucket,group) cursors + bucket_start
    bucket_scan_kernel<<<dim3(1), dim3(1024), 0, stream>>>(hist2, cursor2, bucket_start, row_start, nb, n, E);
    // 4. pass 1: append into bucket sub-regions (line-friendly writes)
    pass1_scatter_kernel<<<dim3(nchunks), dim3(256), 0, stream>>>(erow, ecol, ev, cursor2, tmp, E, chunk);
    // 5. pass 2: exact CSR placement within 32KB windows + row_start
    pass2_kernel<<<dim3(nb), dim3(256), 0, stream>>>(tmp, bucket_start, row_start, edges, n);
    // 6. W1 -> split bf16 transposed
    prep_w1_kernel<<<dim3(512), dim3(256), 0, stream>>>(W1, w1hi, w1lo);
    // 7. h0(bf16) = x @ W1  (split-bf16 MFMA, ~fp32 accurate)
    gemm1_mfma_kernel<<<dim3(2, (n + 127) / 128), dim3(256), 0, stream>>>(x, w1hi, w1lo, h0, n);
    // 8. h1 = relu(spmm(h0))  (bf16 gather, fp32 accum)
    agg1_kernel<<<dim3((n + 3) / 4), dim3(256), 0, stream>>>(h0, row_start, edges, h1, n);
    // 9. BN1 stats
    colstats1_kernel<<<dim3(400), dim3(256), 0, stream>>>(h1, sums1, sumsq1, n, (n + 399) / 400);
    // 10. BN1 params
    bnparams_kernel<<<dim3(1), dim3(256), 0, stream>>>(sums1, sumsq1, g1, b1, scale1, shift1, 256, invN);
    // 11. h2(bf16) = relu(bn1(h1)) @ W2  (fp32 vector ALU, exact)
    gemm2_kernel<<<dim3((n + 127) / 128), dim3(256), 0, stream>>>(h1, W2, scale1, shift1, h2, n);
    // 12. out_pre = relu(spmm(h2))  (bf16 gather, written into d_out)
    agg2_kernel<<<dim3((n + 7) / 8), dim3(256), 0, stream>>>(h2, row_start, edges, out, n);
    // 13. BN2 stats
    colstats2_kernel<<<dim3(200), dim3(256), 0, stream>>>(out, sums2, sumsq2, n, (n + 199) / 200);
    // 14. BN2 params
    bnparams_kernel<<<dim3(1), dim3(64), 0, stream>>>(sums2, sumsq2, g2, b2, scale2, shift2, 64, invN);
    // 15. in-place BN apply on d_out
    bnapply_kernel<<<dim3((n * 64 + 255) / 256), dim3(256), 0, stream>>>(out, scale2, shift2, n * 64);

    (void)n_in; (void)out_size; (void)ws_size;
}